// Round 1
// baseline (305.331 us; speedup 1.0000x reference)
//
#include <hip/hip_runtime.h>
#include <hip/hip_bf16.h>

#define N_ROWS 2048
#define K_DIM  8192
#define MARGIN 0.2f

typedef __attribute__((ext_vector_type(4))) float f32x4;
typedef __bf16 bf16x8 __attribute__((ext_vector_type(8)));

// ---------------- workspace layout ----------------
// [0]                : float accumulator (zeroed via hipMemsetAsync)
// [64]               : inv_c  (2048 f32)
// [64 + 8192]        : inv_a  (2048 f32)
// [32768]            : Cbf    (2048*8192 u16)  33.55 MB
// [32768 + 33554432] : Abf    (2048*8192 u16)  33.55 MB
// total ~64.03 MB

__device__ inline unsigned short f2bf_rne(float f) {
    unsigned int u = __float_as_uint(f);
    unsigned int r = (u + 0x7fffu + ((u >> 16) & 1u)) >> 16;
    return (unsigned short)r;
}

// One block per (row, matrix). Computes 1/max(||row||,eps) and writes a bf16
// copy of the raw (unnormalized) row.
__global__ __launch_bounds__(256) void norm_convert(
    const float* __restrict__ c_in, const float* __restrict__ a_in,
    unsigned short* __restrict__ Cbf, unsigned short* __restrict__ Abf,
    float* __restrict__ invc, float* __restrict__ inva) {
    const int row = blockIdx.x;
    const int which = blockIdx.y;
    const float* src = (which == 0 ? c_in : a_in) + (size_t)row * K_DIM;
    unsigned short* dst = (which == 0 ? Cbf : Abf) + (size_t)row * K_DIM;
    float* invp = (which == 0 ? invc : inva);

    const float4* src4 = (const float4*)src;
    float4 vals[8];
    float s = 0.f;
#pragma unroll
    for (int i = 0; i < 8; ++i) {
        float4 v = src4[threadIdx.x + i * 256];
        vals[i] = v;
        s += v.x * v.x + v.y * v.y + v.z * v.z + v.w * v.w;
    }
    // wave reduce (64 lanes) then cross-wave
#pragma unroll
    for (int off = 32; off; off >>= 1) s += __shfl_down(s, off);
    __shared__ float red[4];
    if ((threadIdx.x & 63) == 0) red[threadIdx.x >> 6] = s;
    __syncthreads();
    if (threadIdx.x == 0) {
        float t = red[0] + red[1] + red[2] + red[3];
        invp[row] = 1.0f / fmaxf(sqrtf(t), 1e-12f);
    }
    // bf16 conversion (independent of the norm)
#pragma unroll
    for (int i = 0; i < 8; ++i) {
        float4 v = vals[i];
        ushort4 o;
        o.x = f2bf_rne(v.x);
        o.y = f2bf_rne(v.y);
        o.z = f2bf_rne(v.z);
        o.w = f2bf_rne(v.w);
        ((ushort4*)dst)[threadIdx.x + i * 256] = o;
    }
}

// 128x128 tile, BK=64, 4 waves (each wave -> 64x64 = 4x4 fragments of 16x16),
// mfma_f32_16x16x32_bf16, global_load_lds width-16 staging, fused epilogue.
__global__ __launch_bounds__(256) void gemm_loss(
    const unsigned short* __restrict__ Cbf, const unsigned short* __restrict__ Abf,
    const float* __restrict__ invc, const float* __restrict__ inva,
    float* __restrict__ acc_out) {
    __shared__ unsigned short ldsA[128 * 64];
    __shared__ unsigned short ldsB[128 * 64];

    // XCD-aware swizzle: 256 blocks, 8 XCDs -> contiguous 32-block chunks/XCD
    const int b = blockIdx.x;
    const int swz = (b & 7) * 32 + (b >> 3);
    const int bx = swz & 15;   // N-tile (audio cols)
    const int by = swz >> 4;   // M-tile (content rows)

    const int tid  = threadIdx.x;
    const int lane = tid & 63;
    const int w    = tid >> 6;
    const int wr   = w >> 1;   // wave row 0..1
    const int wc   = w & 1;    // wave col 0..1

    f32x4 acc[4][4];
#pragma unroll
    for (int i = 0; i < 4; ++i)
#pragma unroll
        for (int j = 0; j < 4; ++j) acc[i][j] = (f32x4)0.f;

    // staging geometry: chunk = r*4 + w (8 rows of 64 cols = 512 elems = 1KB);
    // lane l covers 8 elems at elem off = chunk*512 + l*8
    const int lrow = lane >> 3;        // 0..7 within chunk
    const int lcol = (lane & 7) * 8;   // 0..56

    const unsigned short* gA = Cbf + (size_t)(by * 128) * K_DIM;
    const unsigned short* gB = Abf + (size_t)(bx * 128) * K_DIM;

    for (int k0 = 0; k0 < K_DIM; k0 += 64) {
        __syncthreads();   // previous tile's compute done before overwrite
#pragma unroll
        for (int r = 0; r < 4; ++r) {
            const int chunk = r * 4 + w;
            const int row = chunk * 8 + lrow;
            const unsigned short* src = gA + (size_t)row * K_DIM + k0 + lcol;
            __builtin_amdgcn_global_load_lds(
                (const __attribute__((address_space(1))) unsigned int*)src,
                (__attribute__((address_space(3))) unsigned int*)&ldsA[chunk * 512],
                16, 0, 0);
        }
#pragma unroll
        for (int r = 0; r < 4; ++r) {
            const int chunk = r * 4 + w;
            const int row = chunk * 8 + lrow;
            const unsigned short* src = gB + (size_t)row * K_DIM + k0 + lcol;
            __builtin_amdgcn_global_load_lds(
                (const __attribute__((address_space(1))) unsigned int*)src,
                (__attribute__((address_space(3))) unsigned int*)&ldsB[chunk * 512],
                16, 0, 0);
        }
        __syncthreads();   // staging complete (compiler drains vmcnt here)

#pragma unroll
        for (int kk = 0; kk < 64; kk += 32) {
            bf16x8 af[4], bfr[4];
            const int krd = kk + (lane >> 4) * 8;
            const int rsel = lane & 15;
#pragma unroll
            for (int mi = 0; mi < 4; ++mi)
                af[mi] = *(const bf16x8*)&ldsA[(wr * 64 + mi * 16 + rsel) * 64 + krd];
#pragma unroll
            for (int ni = 0; ni < 4; ++ni)
                bfr[ni] = *(const bf16x8*)&ldsB[(wc * 64 + ni * 16 + rsel) * 64 + krd];
#pragma unroll
            for (int mi = 0; mi < 4; ++mi)
#pragma unroll
                for (int ni = 0; ni < 4; ++ni)
                    acc[mi][ni] = __builtin_amdgcn_mfma_f32_16x16x32_bf16(
                        af[mi], bfr[ni], acc[mi][ni], 0, 0, 0);
        }
    }

    // ---- fused epilogue ----
    const int row0 = by * 128 + wr * 64;
    const int col0 = bx * 128 + wc * 64;
    float ia[4];
#pragma unroll
    for (int ni = 0; ni < 4; ++ni) ia[ni] = inva[col0 + ni * 16 + (lane & 15)];
    float ic[4][4];
#pragma unroll
    for (int mi = 0; mi < 4; ++mi)
#pragma unroll
        for (int r = 0; r < 4; ++r)
            ic[mi][r] = invc[row0 + mi * 16 + (lane >> 4) * 4 + r];

    float local = 0.f;
#pragma unroll
    for (int mi = 0; mi < 4; ++mi) {
#pragma unroll
        for (int ni = 0; ni < 4; ++ni) {
            const int col = col0 + ni * 16 + (lane & 15);
            const int rbase = row0 + mi * 16 + (lane >> 4) * 4;
#pragma unroll
            for (int r = 0; r < 4; ++r) {
                const float sim = acc[mi][ni][r] * ic[mi][r] * ia[ni];
                const float d2 = fmaxf(2.f - 2.f * sim, 0.f);
                if (rbase + r == col) {
                    local += d2;                       // diagonal_dist^2
                } else {
                    float t = fmaxf(MARGIN - sqrtf(d2), 0.f);
                    local += t * t;                    // cost_s^2
                }
            }
        }
    }
#pragma unroll
    for (int off = 32; off; off >>= 1) local += __shfl_down(local, off);
    __shared__ float red[4];
    if (lane == 0) red[w] = local;
    __syncthreads();
    if (tid == 0) atomicAdd(acc_out, red[0] + red[1] + red[2] + red[3]);
}

__global__ void finalize(const float* __restrict__ acc, float* __restrict__ out) {
    if (threadIdx.x == 0 && blockIdx.x == 0)
        out[0] = acc[0] / (2.0f * N_ROWS);
}

extern "C" void kernel_launch(void* const* d_in, const int* in_sizes, int n_in,
                              void* d_out, int out_size, void* d_ws, size_t ws_size,
                              hipStream_t stream) {
    const float* c_in = (const float*)d_in[0];
    const float* a_in = (const float*)d_in[1];
    float* out = (float*)d_out;

    char* ws = (char*)d_ws;
    float* accp = (float*)ws;
    float* invc = (float*)(ws + 64);
    float* inva = (float*)(ws + 64 + 2048 * 4);
    unsigned short* Cbf = (unsigned short*)(ws + 32768);
    unsigned short* Abf = Cbf + (size_t)N_ROWS * K_DIM;

    hipMemsetAsync(d_ws, 0, 64, stream);
    norm_convert<<<dim3(N_ROWS, 2), 256, 0, stream>>>(c_in, a_in, Cbf, Abf, invc, inva);
    gemm_loss<<<dim3(256), 256, 0, stream>>>(Cbf, Abf, invc, inva, accp);
    finalize<<<1, 64, 0, stream>>>(accp, out);
}